// Round 7
// baseline (55.193 us; speedup 1.0000x reference)
//
#include <hip/hip_runtime.h>

#define DIM 4096
#define NE 8

// ---------------------------------------------------------------------------
// int8 4-way dot:  c += sum_k a.byte[k] * b.byte[k]   (signed)
// ---------------------------------------------------------------------------
#if __has_builtin(__builtin_amdgcn_sdot4)
__device__ __forceinline__ int dot4(int a, int b, int c) {
    return __builtin_amdgcn_sdot4(a, b, c, false);
}
#else
__device__ __forceinline__ int dot4(int a, int b, int c) {
    #pragma unroll
    for (int k = 0; k < 4; ++k)
        c += (int)(signed char)(a >> (8 * k)) * (int)(signed char)(b >> (8 * k));
    return c;
}
#endif

// pack low bytes of 4 ints into one dword: [q3|q2|q1|q0]
__device__ __forceinline__ unsigned pack4(int q0, int q1, int q2, int q3) {
    unsigned t0 = __builtin_amdgcn_perm((unsigned)q1, (unsigned)q0, 0x00000400u);
    unsigned t1 = __builtin_amdgcn_perm((unsigned)q3, (unsigned)q2, 0x00000400u);
    return __builtin_amdgcn_perm(t1, t0, 0x05040100u);
}

// ---------------------------------------------------------------------------
// Kernel 1 (fused): mean|W| + ternary quant + pack, single block, W read once.
// Output layout GROUP-MAJOR: wq32[g*NE + e] packs elements 4g..4g+3 of expert
// e — a gate lane reads its 8 experts as 2 contiguous uint4s.
// ---------------------------------------------------------------------------
__global__ __launch_bounds__(1024) void wq_kernel(const float* __restrict__ W,
                                                  unsigned* __restrict__ wq32,
                                                  float* __restrict__ wscale) {
    __shared__ float red[16];
    const int tid = threadIdx.x, lane = tid & 63, wid = tid >> 6;

    const float4* W4 = (const float4*)W;       // 8192 float4s
    float4 w[8];
    float s = 0.f;
    #pragma unroll
    for (int i = 0; i < 8; ++i) {
        w[i] = W4[i * 1024 + tid];
        s += fabsf(w[i].x) + fabsf(w[i].y) + fabsf(w[i].z) + fabsf(w[i].w);
    }
    #pragma unroll
    for (int o = 32; o > 0; o >>= 1) s += __shfl_xor(s, o, 64);
    if (lane == 0) red[wid] = s;
    __syncthreads();
    float tot = 0.f;
    #pragma unroll
    for (int k = 0; k < 16; ++k) tot += red[k];
    const float ws = 1.0f / fmaxf(tot * (1.0f / (NE * DIM)), 1e-5f);
    if (tid == 0) *wscale = ws;

    #pragma unroll
    for (int i = 0; i < 8; ++i) {
        const int idx = i * 1024 + tid;        // e-major dword index = e*1024+g
        const int e = idx >> 10;
        const int g = idx & 1023;
        const int q0 = min(max((int)rintf(w[i].x * ws), -1), 1);
        const int q1 = min(max((int)rintf(w[i].y * ws), -1), 1);
        const int q2 = min(max((int)rintf(w[i].z * ws), -1), 1);
        const int q3 = min(max((int)rintf(w[i].w * ws), -1), 1);
        wq32[g * NE + e] = pack4(q0, q1, q2, q3);
    }
}

// ---------------------------------------------------------------------------
// Kernel 2: ONE WAVE = ONE TOKEN. No __syncthreads, no LDS; 16 dwordx4 HBM
// loads in flight per lane; all reductions are wave-local shuffles; weight
// loads (L2-hot) software-pipelined one iteration ahead.
// (Plain vector loads — NT hint measured 23% SLOWER on gfx950, R4.)
// ---------------------------------------------------------------------------
__global__ __launch_bounds__(256) void gate_kernel(const float* __restrict__ x,
                                                   const unsigned* __restrict__ wq32,
                                                   const float* __restrict__ wscale,
                                                   const float* __restrict__ bias,
                                                   float* __restrict__ out) {
    const int lane = threadIdx.x & 63;
    const int wv   = threadIdx.x >> 6;
    const size_t token = (size_t)blockIdx.x * 4 + wv;
    const float4* xrow = (const float4*)(x + token * (size_t)DIM);

    // ---- stream full row into registers: 16 outstanding HBM loads/lane ----
    float4 v[16];
    #pragma unroll
    for (int r = 0; r < 16; ++r) v[r] = xrow[r * 64 + lane];

    // ---- sumsq + absmax over the row (wave-local) ----
    float ss = 0.f, amax = 0.f;
    #pragma unroll
    for (int r = 0; r < 16; ++r) {
        ss = fmaf(v[r].x, v[r].x, ss);
        ss = fmaf(v[r].y, v[r].y, ss);
        ss = fmaf(v[r].z, v[r].z, ss);
        ss = fmaf(v[r].w, v[r].w, ss);
        amax = fmaxf(amax, fmaxf(fmaxf(fabsf(v[r].x), fabsf(v[r].y)),
                                 fmaxf(fabsf(v[r].z), fabsf(v[r].w))));
    }
    #pragma unroll
    for (int o = 32; o > 0; o >>= 1) {
        ss  += __shfl_xor(ss, o, 64);
        amax = fmaxf(amax, __shfl_xor(amax, o, 64));
    }

    const float n     = fmaxf(sqrtf(ss), 1e-12f);
    const float xnmax = (amax / n) * 64.0f;               // max|xn|
    const float scale = 127.0f / fmaxf(xnmax, 1e-5f);     // act-quant scale
    const float m     = (64.0f / n) * scale;              // x -> q multiplier

    // ---- quantize + 8 ternary dots, weights pipelined one iter ahead ----
    const uint4* wp = (const uint4*)wq32;     // 2 uint4 per 4-elem group
    int acc[NE] = {0, 0, 0, 0, 0, 0, 0, 0};
    uint4 wa = wp[(0 * 64 + lane) * 2 + 0];
    uint4 wb = wp[(0 * 64 + lane) * 2 + 1];
    #pragma unroll
    for (int r = 0; r < 16; ++r) {
        uint4 na, nb;
        if (r < 15) {
            na = wp[((r + 1) * 64 + lane) * 2 + 0];
            nb = wp[((r + 1) * 64 + lane) * 2 + 1];
        }
        const int q0 = (int)rintf(v[r].x * m);            // |q|<=127 by construction
        const int q1 = (int)rintf(v[r].y * m);
        const int q2 = (int)rintf(v[r].z * m);
        const int q3 = (int)rintf(v[r].w * m);
        const int packed = (int)pack4(q0, q1, q2, q3);
        acc[0] = dot4(packed, (int)wa.x, acc[0]);
        acc[1] = dot4(packed, (int)wa.y, acc[1]);
        acc[2] = dot4(packed, (int)wa.z, acc[2]);
        acc[3] = dot4(packed, (int)wa.w, acc[3]);
        acc[4] = dot4(packed, (int)wb.x, acc[4]);
        acc[5] = dot4(packed, (int)wb.y, acc[5]);
        acc[6] = dot4(packed, (int)wb.z, acc[6]);
        acc[7] = dot4(packed, (int)wb.w, acc[7]);
        wa = na; wb = nb;
    }

    // ---- value-splitting butterfly: lane ends with full-wave sum of expert lane&7 ----
    #pragma unroll
    for (int j = 0; j < 4; ++j) {
        const int give = (lane & 1) ? acc[2*j] : acc[2*j+1];
        const int got  = __shfl_xor(give, 1, 64);
        const int keep = (lane & 1) ? acc[2*j+1] : acc[2*j];
        acc[j] = keep + got;
    }
    #pragma unroll
    for (int j = 0; j < 2; ++j) {
        const int give = (lane & 2) ? acc[2*j] : acc[2*j+1];
        const int got  = __shfl_xor(give, 2, 64);
        const int keep = (lane & 2) ? acc[2*j+1] : acc[2*j];
        acc[j] = keep + got;
    }
    {
        const int give = (lane & 4) ? acc[0] : acc[1];
        const int got  = __shfl_xor(give, 4, 64);
        const int keep = (lane & 4) ? acc[1] : acc[0];
        acc[0] = keep + got;
    }
    #pragma unroll
    for (int o = 8; o < 64; o <<= 1) acc[0] += __shfl_xor(acc[0], o, 64);

    // ---- epilogue: lanes 0..7 do bias + softmax, one 32B store per wave ----
    if (lane < NE) {
        const float inv = 1.0f / (scale * (*wscale));
        float logit = (float)acc[0] * inv + bias[lane];
        float mx = logit;
        #pragma unroll
        for (int o = 1; o < NE; o <<= 1) mx = fmaxf(mx, __shfl_xor(mx, o, 64));
        const float p = expf(logit - mx);
        float s = p;
        #pragma unroll
        for (int o = 1; o < NE; o <<= 1) s += __shfl_xor(s, o, 64);
        out[token * NE + lane] = p / s;
    }
}

// ---------------------------------------------------------------------------
extern "C" void kernel_launch(void* const* d_in, const int* in_sizes, int n_in,
                              void* d_out, int out_size, void* d_ws, size_t ws_size,
                              hipStream_t stream) {
    const float* x = (const float*)d_in[0];   // [4,4096,4096] fp32
    const float* W = (const float*)d_in[1];   // [8,4096] fp32
    const float* b = (const float*)d_in[2];   // [8] fp32
    float* out = (float*)d_out;               // [4,4096,8] fp32

    unsigned* wq32   = (unsigned*)d_ws;                          // 32 KB packed ternary
    float* wscale    = (float*)((char*)d_ws + 32768);            // 1 float

    const int tokens = in_sizes[0] / DIM;     // 16384

    wq_kernel<<<1, 1024, 0, stream>>>(W, wq32, wscale);
    gate_kernel<<<tokens / 4, 256, 0, stream>>>(x, wq32, wscale, b, out);
}

// Round 8
// 50.812 us; speedup vs baseline: 1.0862x; 1.0862x over previous
//
#include <hip/hip_runtime.h>

#define DIM 4096
#define NE 8

// ---------------------------------------------------------------------------
// int8 4-way dot:  c += sum_k a.byte[k] * b.byte[k]   (signed)
// ---------------------------------------------------------------------------
#if __has_builtin(__builtin_amdgcn_sdot4)
__device__ __forceinline__ int dot4(int a, int b, int c) {
    return __builtin_amdgcn_sdot4(a, b, c, false);
}
#else
__device__ __forceinline__ int dot4(int a, int b, int c) {
    #pragma unroll
    for (int k = 0; k < 4; ++k)
        c += (int)(signed char)(a >> (8 * k)) * (int)(signed char)(b >> (8 * k));
    return c;
}
#endif

// pack low bytes of 4 ints into one dword: [q3|q2|q1|q0]
__device__ __forceinline__ unsigned pack4(int q0, int q1, int q2, int q3) {
    unsigned t0 = __builtin_amdgcn_perm((unsigned)q1, (unsigned)q0, 0x00000400u);
    unsigned t1 = __builtin_amdgcn_perm((unsigned)q3, (unsigned)q2, 0x00000400u);
    return __builtin_amdgcn_perm(t1, t0, 0x05040100u);
}

// ---------------------------------------------------------------------------
// Kernel 1 (fused): mean|W| + ternary quant + pack, single block, W read once.
// Output layout GROUP-MAJOR: wq32[g*NE + e] packs elements 4g..4g+3 of expert
// e — a gate thread reads its 8 experts as 2 contiguous uint4s.
// ---------------------------------------------------------------------------
__global__ __launch_bounds__(1024) void wq_kernel(const float* __restrict__ W,
                                                  unsigned* __restrict__ wq32,
                                                  float* __restrict__ wscale) {
    __shared__ float red[16];
    const int tid = threadIdx.x, lane = tid & 63, wid = tid >> 6;

    const float4* W4 = (const float4*)W;       // 8192 float4s
    float4 w[8];
    float s = 0.f;
    #pragma unroll
    for (int i = 0; i < 8; ++i) {
        w[i] = W4[i * 1024 + tid];
        s += fabsf(w[i].x) + fabsf(w[i].y) + fabsf(w[i].z) + fabsf(w[i].w);
    }
    #pragma unroll
    for (int o = 32; o > 0; o >>= 1) s += __shfl_xor(s, o, 64);
    if (lane == 0) red[wid] = s;
    __syncthreads();
    float tot = 0.f;
    #pragma unroll
    for (int k = 0; k < 16; ++k) tot += red[k];
    const float ws = 1.0f / fmaxf(tot * (1.0f / (NE * DIM)), 1e-5f);
    if (tid == 0) *wscale = ws;

    #pragma unroll
    for (int i = 0; i < 8; ++i) {
        const int idx = i * 1024 + tid;        // e-major dword index = e*1024+g
        const int e = idx >> 10;
        const int g = idx & 1023;
        const int q0 = min(max((int)rintf(w[i].x * ws), -1), 1);
        const int q1 = min(max((int)rintf(w[i].y * ws), -1), 1);
        const int q2 = min(max((int)rintf(w[i].z * ws), -1), 1);
        const int q3 = min(max((int)rintf(w[i].w * ws), -1), 1);
        wq32[g * NE + e] = pack4(q0, q1, q2, q3);
    }
}

// ---------------------------------------------------------------------------
// Kernel 2: per-token fused rmsnorm + int8 act-quant + 8 ternary dots (sdot4)
// + softmax. One block per token; row read from HBM once into registers.
// Best measured shape (R6): 256-thread blocks, high occupancy, many blocks.
// (NT hints: 23% SLOWER on gfx950 (R4). Wave-per-token fat regs: 8% slower (R7).)
// ---------------------------------------------------------------------------
__global__ __launch_bounds__(256) void gate_kernel(const float* __restrict__ x,
                                                   const unsigned* __restrict__ wq32,
                                                   const float* __restrict__ wscale,
                                                   const float* __restrict__ bias,
                                                   float* __restrict__ out) {
    __shared__ float sred[4], ared[4];
    __shared__ int accred[4][NE];

    const int tid = threadIdx.x, lane = tid & 63, wid = tid >> 6;
    const size_t token = blockIdx.x;
    const float4* xrow = (const float4*)(x + token * (size_t)DIM);

    // ---- HBM x-loads first: they own the front of the VMEM queue ----
    float4 v[4];
    #pragma unroll
    for (int r = 0; r < 4; ++r) v[r] = xrow[r * 256 + tid];

    // ---- weight dwords: 2 coalesced uint4 loads per r (L2-hot) ----
    uint4 wa[4], wb[4];
    #pragma unroll
    for (int r = 0; r < 4; ++r) {
        const int e4 = r * 256 + tid;                  // group index 0..1023
        const uint4* wp = (const uint4*)(wq32 + (size_t)e4 * NE);
        wa[r] = wp[0];                                 // experts 0..3
        wb[r] = wp[1];                                 // experts 4..7
    }

    // ---- pass 1: sumsq + absmax ----
    float ss = 0.f, amax = 0.f;
    #pragma unroll
    for (int r = 0; r < 4; ++r) {
        ss = fmaf(v[r].x, v[r].x, ss);
        ss = fmaf(v[r].y, v[r].y, ss);
        ss = fmaf(v[r].z, v[r].z, ss);
        ss = fmaf(v[r].w, v[r].w, ss);
        amax = fmaxf(amax, fmaxf(fmaxf(fabsf(v[r].x), fabsf(v[r].y)),
                                 fmaxf(fabsf(v[r].z), fabsf(v[r].w))));
    }
    #pragma unroll
    for (int o = 32; o > 0; o >>= 1) {
        ss  += __shfl_xor(ss, o, 64);
        amax = fmaxf(amax, __shfl_xor(amax, o, 64));
    }
    if (lane == 0) { sred[wid] = ss; ared[wid] = amax; }
    __syncthreads();
    ss   = sred[0] + sred[1] + sred[2] + sred[3];
    amax = fmaxf(fmaxf(ared[0], ared[1]), fmaxf(ared[2], ared[3]));

    const float n     = fmaxf(sqrtf(ss), 1e-12f);
    const float xnmax = (amax / n) * 64.0f;               // max|xn|
    const float scale = 127.0f / fmaxf(xnmax, 1e-5f);     // act-quant scale
    const float m     = (64.0f / n) * scale;              // x -> q multiplier

    // ---- pass 2: quantize in-register + sdot4 against 8 experts ----
    int acc[NE] = {0, 0, 0, 0, 0, 0, 0, 0};
    #pragma unroll
    for (int r = 0; r < 4; ++r) {
        const int q0 = (int)rintf(v[r].x * m);            // |q|<=127 by construction
        const int q1 = (int)rintf(v[r].y * m);
        const int q2 = (int)rintf(v[r].z * m);
        const int q3 = (int)rintf(v[r].w * m);
        const int packed = (int)pack4(q0, q1, q2, q3);
        acc[0] = dot4(packed, (int)wa[r].x, acc[0]);
        acc[1] = dot4(packed, (int)wa[r].y, acc[1]);
        acc[2] = dot4(packed, (int)wa[r].z, acc[2]);
        acc[3] = dot4(packed, (int)wa[r].w, acc[3]);
        acc[4] = dot4(packed, (int)wb[r].x, acc[4]);
        acc[5] = dot4(packed, (int)wb[r].y, acc[5]);
        acc[6] = dot4(packed, (int)wb[r].z, acc[6]);
        acc[7] = dot4(packed, (int)wb[r].w, acc[7]);
    }

    // ---- value-splitting butterfly: lane ends with full-wave sum of expert lane&7 ----
    #pragma unroll
    for (int j = 0; j < 4; ++j) {
        const int give = (lane & 1) ? acc[2*j] : acc[2*j+1];
        const int got  = __shfl_xor(give, 1, 64);
        const int keep = (lane & 1) ? acc[2*j+1] : acc[2*j];
        acc[j] = keep + got;
    }
    #pragma unroll
    for (int j = 0; j < 2; ++j) {
        const int give = (lane & 2) ? acc[2*j] : acc[2*j+1];
        const int got  = __shfl_xor(give, 2, 64);
        const int keep = (lane & 2) ? acc[2*j+1] : acc[2*j];
        acc[j] = keep + got;
    }
    {
        const int give = (lane & 4) ? acc[0] : acc[1];
        const int got  = __shfl_xor(give, 4, 64);
        const int keep = (lane & 4) ? acc[1] : acc[0];
        acc[0] = keep + got;
    }
    #pragma unroll
    for (int o = 8; o < 64; o <<= 1) acc[0] += __shfl_xor(acc[0], o, 64);

    if (lane < NE) accred[wid][lane] = acc[0];
    __syncthreads();

    // ---- epilogue: lanes 0..7 do bias + softmax, one coalesced 32B store ----
    if (tid < NE) {
        const float inv = 1.0f / (scale * (*wscale));
        const int tot = accred[0][tid] + accred[1][tid] + accred[2][tid] + accred[3][tid];
        float logit = (float)tot * inv + bias[tid];
        float mx = logit;
        #pragma unroll
        for (int o = 1; o < NE; o <<= 1) mx = fmaxf(mx, __shfl_xor(mx, o, 64));
        const float p = expf(logit - mx);
        float s = p;
        #pragma unroll
        for (int o = 1; o < NE; o <<= 1) s += __shfl_xor(s, o, 64);
        out[token * NE + tid] = p / s;
    }
}

// ---------------------------------------------------------------------------
extern "C" void kernel_launch(void* const* d_in, const int* in_sizes, int n_in,
                              void* d_out, int out_size, void* d_ws, size_t ws_size,
                              hipStream_t stream) {
    const float* x = (const float*)d_in[0];   // [4,4096,4096] fp32
    const float* W = (const float*)d_in[1];   // [8,4096] fp32
    const float* b = (const float*)d_in[2];   // [8] fp32
    float* out = (float*)d_out;               // [4,4096,8] fp32

    unsigned* wq32   = (unsigned*)d_ws;                          // 32 KB packed ternary
    float* wscale    = (float*)((char*)d_ws + 32768);            // 1 float

    const int tokens = in_sizes[0] / DIM;     // 16384

    wq_kernel<<<1, 1024, 0, stream>>>(W, wq32, wscale);
    gate_kernel<<<tokens, 256, 0, stream>>>(x, wq32, wscale, b, out);
}